// Round 8
// baseline (326.306 us; speedup 1.0000x reference)
//
#include <hip/hip_runtime.h>
#include <hip/hip_fp8.h>
#include <math.h>

#define NUM_NODES 150000
#define DIM 64
#define N_EDGES 3200000
#define BATCH 1024
#define N_NEGS 40
#define REG_COEF 1e-4f

#define BK_BITS 9
#define BK_NODES 512
#define NBK ((NUM_NODES + BK_NODES - 1) >> BK_BITS)      // 293
#define TILE 8192
#define NT ((N_EDGES + TILE - 1) / TILE)                 // 391
#define HSIZE (NBK * NT)                                 // 114563
#define SCAN_B 1024
#define NB2 ((HSIZE + SCAN_B - 1) / SCAN_B)              // 112
#define NLIST (BATCH * (N_NEGS + 2))                     // 43008

typedef _Float16 half2v __attribute__((ext_vector_type(2)));
typedef _Float16 half4v __attribute__((ext_vector_type(4)));

// ---------------- pass 1: per-tile bucket histogram ----------------
__global__ __launch_bounds__(256) void histo_kernel(const int* __restrict__ col,
                                                    int* __restrict__ hist) {
    __shared__ int h[NBK];
    int t = threadIdx.x;
    for (int i = t; i < NBK; i += 256) h[i] = 0;
    __syncthreads();
    int e0 = blockIdx.x * TILE;
    int e1 = e0 + TILE; if (e1 > N_EDGES) e1 = N_EDGES;
    for (int i = e0 + t; i < e1; i += 256) atomicAdd(&h[col[i] >> BK_BITS], 1);
    __syncthreads();
    for (int i = t; i < NBK; i += 256) hist[i * NT + blockIdx.x] = h[i];
}

// ---------------- scan (3 kernels) over hist[HSIZE] -> exclusive in-place ----------------
__global__ void scan_partial_kernel(const int* __restrict__ src, int* __restrict__ partial, int n) {
    int t = threadIdx.x;
    int g = blockIdx.x * SCAN_B + t;
    int v = (g < n) ? src[g] : 0;
    for (int m = 1; m < 64; m <<= 1) v += __shfl_xor(v, m);
    __shared__ int ws[16];
    if ((t & 63) == 0) ws[t >> 6] = v;
    __syncthreads();
    if (t < 16) {
        int s = ws[t];
        for (int m = 1; m < 16; m <<= 1) s += __shfl_xor(s, m);
        if (t == 0) partial[blockIdx.x] = s;
    }
}

__global__ void scan_base_kernel(int* __restrict__ partial, int nb, int chunks) {
    int l = threadIdx.x;
    int carry = 0;
    for (int c = 0; c < chunks; c++) {
        int idx = c * 64 + l;
        int v = (idx < nb) ? partial[idx] : 0;
        int inc = v;
        for (int m = 1; m < 64; m <<= 1) {
            int t = __shfl_up(inc, m);
            if (l >= m) inc += t;
        }
        int excl = inc - v + carry;
        if (idx < nb) partial[idx] = excl;
        carry += __shfl(inc, 63);
    }
}

__global__ void scan_apply_kernel(int* __restrict__ data, const int* __restrict__ partial, int n) {
    __shared__ int lds[SCAN_B];
    int t = threadIdx.x;
    int g = blockIdx.x * SCAN_B + t;
    int v = (g < n) ? data[g] : 0;
    int val = v;
    lds[t] = val;
    __syncthreads();
    for (int o = 1; o < SCAN_B; o <<= 1) {
        int add = (t >= o) ? lds[t - o] : 0;
        __syncthreads();
        val += add;
        lds[t] = val;
        __syncthreads();
    }
    if (g < n) data[g] = partial[blockIdx.x] + val - v;  // exclusive
}

// ---------------- pass 2: rank-based partition into bucket-grouped staging ----------------
__global__ __launch_bounds__(256) void partition_kernel(const int* __restrict__ row,
                                                        const int* __restrict__ col,
                                                        const int* __restrict__ hist,
                                                        unsigned* __restrict__ staging) {
    __shared__ int base[NBK];
    __shared__ int cnt[NBK];
    int t = threadIdx.x;
    for (int i = t; i < NBK; i += 256) { base[i] = hist[i * NT + blockIdx.x]; cnt[i] = 0; }
    __syncthreads();
    int e0 = blockIdx.x * TILE;
    int e1 = e0 + TILE; if (e1 > N_EDGES) e1 = N_EDGES;
    for (int i = e0 + t; i < e1; i += 256) {
        int c = col[i];
        int b = c >> BK_BITS;
        int r = atomicAdd(&cnt[b], 1);
        staging[base[b] + r] = ((unsigned)(c & (BK_NODES - 1)) << 18) | (unsigned)row[i];
    }
}

// ------ pass 3: per-bucket offsets + dinv + sq + CSR + pre-scaled fp8 E (x16 scale) ------
__global__ __launch_bounds__(512) void fill3_kernel(const int* __restrict__ hist,
                                                    const unsigned* __restrict__ staging,
                                                    const float* __restrict__ E,
                                                    int* __restrict__ off,
                                                    float* __restrict__ dinv,
                                                    float* __restrict__ sq,
                                                    int* __restrict__ csr_row,
                                                    __hip_fp8x4_e4m3* __restrict__ xnE4) {
    __shared__ int cnt[BK_NODES];
    __shared__ int lds[BK_NODES];
    __shared__ float sdinv[BK_NODES];
    int b = blockIdx.x;
    int t = threadIdx.x;
    int node0 = b << BK_BITS;
    int bstart = hist[b * NT];
    int bend = (b + 1 < NBK) ? hist[(b + 1) * NT] : N_EDGES;
    cnt[t] = 0;
    __syncthreads();
    for (int i = bstart + t; i < bend; i += 512) atomicAdd(&cnt[staging[i] >> 18], 1);
    __syncthreads();
    int v = cnt[t];
    int val = v;
    lds[t] = val;
    __syncthreads();
    for (int o = 1; o < BK_NODES; o <<= 1) {
        int add = (t >= o) ? lds[t - o] : 0;
        __syncthreads();
        val += add;
        lds[t] = val;
        __syncthreads();
    }
    int cursor = bstart + val - v;   // exclusive
    int node = node0 + t;
    float dv = (v > 0) ? rsqrtf((float)v) : 0.f;
    if (node < NUM_NODES) {
        off[node] = cursor;
        dinv[node] = dv;
        sq[node] = sqrtf((float)v);
    }
    sdinv[t] = dv;
    cnt[t] = cursor;
    __syncthreads();
    for (int i = bstart + t; i < bend; i += 512) {
        unsigned s = staging[i];
        int pos = atomicAdd(&cnt[s >> 18], 1);
        csr_row[pos] = (int)(s & 0x3FFFFu);
    }
    // pre-scaled fp8 operand: xnE[node] = e4m3( 16 * dinv[node] * E[node] )
    int nvalid = NUM_NODES - node0; if (nvalid > BK_NODES) nvalid = BK_NODES;
    int groups = nvalid << 4;                         // 16 float4-groups per row
    const float4* E4 = (const float4*)E + ((size_t)node0 << 4);
    __hip_fp8x4_e4m3* out4 = xnE4 + ((size_t)node0 << 4);
    for (int gi = t; gi < groups; gi += 512) {
        float4 e = E4[gi];
        float s = 16.f * sdinv[gi >> 4];
        out4[gi] = __hip_fp8x4_e4m3(make_float4(s * e.x, s * e.y, s * e.z, s * e.w));
    }
    if (b == 0 && t == 0) off[NUM_NODES] = N_EDGES;
}

// ---------------- mark + compact the ~39K nodes the loss actually touches ------------
__global__ void flag_kernel(const int* __restrict__ u, const int* __restrict__ v,
                            const int* __restrict__ n, char* __restrict__ flags) {
    int i = blockIdx.x * blockDim.x + threadIdx.x;
    if (i >= NLIST) return;
    int id;
    if (i < BATCH) id = u[i];
    else if (i < 2 * BATCH) id = v[i - BATCH];
    else id = n[i - 2 * BATCH];
    flags[id] = 1;
}

__global__ void compact_kernel(const char* __restrict__ flags, int* __restrict__ list,
                               int* __restrict__ count) {
    int i = blockIdx.x * blockDim.x + threadIdx.x;
    if (i < NUM_NODES && flags[i]) {
        int pos = atomicAdd(count, 1);
        list[pos] = i;
    }
}

// ---- conv layer 1 (full graph, fp8 operand, one 16-lane group per node) ----
__global__ __launch_bounds__(256) void conv1_kernel(const int* __restrict__ off,
                                                    const int* __restrict__ csr_row,
                                                    const float* __restrict__ dinv,
                                                    const __hip_fp8x4_e4m3* __restrict__ xq,
                                                    _Float16* __restrict__ yh) {
    int gid = blockIdx.x * blockDim.x + threadIdx.x;
    int grp = gid >> 4;               // node index
    int g = threadIdx.x & 15;         // dim group
    if (grp >= NUM_NODES) return;
    int start = off[grp];
    int end = off[grp + 1];
    float a0 = 0.f, a1 = 0.f, a2 = 0.f, a3 = 0.f;
    int i = start;
    for (; i + 3 < end; i += 4) {
        int r0 = csr_row[i];
        int r1 = csr_row[i + 1];
        int r2 = csr_row[i + 2];
        int r3 = csr_row[i + 3];
        float4 v0 = static_cast<float4>(xq[((size_t)r0 << 4) + g]);
        float4 v1 = static_cast<float4>(xq[((size_t)r1 << 4) + g]);
        float4 v2 = static_cast<float4>(xq[((size_t)r2 << 4) + g]);
        float4 v3 = static_cast<float4>(xq[((size_t)r3 << 4) + g]);
        a0 += v0.x + v1.x + v2.x + v3.x;
        a1 += v0.y + v1.y + v2.y + v3.y;
        a2 += v0.z + v1.z + v2.z + v3.z;
        a3 += v0.w + v1.w + v2.w + v3.w;
    }
    for (; i < end; ++i) {
        int r = csr_row[i];
        float4 v = static_cast<float4>(xq[((size_t)r << 4) + g]);
        a0 += v.x; a1 += v.y; a2 += v.z; a3 += v.w;
    }
    float dv = dinv[grp];
    float s = dv * dv * (1.f / 16.f);
    union { _Float16 h[4]; short4 s4; } u;
    u.h[0] = (_Float16)(s * a0);
    u.h[1] = (_Float16)(s * a1);
    u.h[2] = (_Float16)(s * a2);
    u.h[3] = (_Float16)(s * a3);
    ((short4*)yh)[((size_t)grp << 4) + g] = u.s4;
}

// ---- conv layer 2 (listed nodes, fp16 operand, one 16-lane group per node) ----
__global__ __launch_bounds__(256) void conv2_kernel(const int* __restrict__ off,
                                                    const int* __restrict__ csr_row,
                                                    const float* __restrict__ dinv,
                                                    const _Float16* __restrict__ xh,
                                                    float* __restrict__ x2,
                                                    const int* __restrict__ list,
                                                    const int* __restrict__ count) {
    int gid = blockIdx.x * blockDim.x + threadIdx.x;
    int li = gid >> 4;
    int g = threadIdx.x & 15;
    if (li >= *count) return;
    int nd = list[li];
    int start = off[nd];
    int end = off[nd + 1];
    const short4* xh4 = (const short4*)xh;
    float a0 = 0.f, a1 = 0.f, a2 = 0.f, a3 = 0.f;
    int i = start;
    for (; i + 3 < end; i += 4) {
        int r0 = csr_row[i];
        int r1 = csr_row[i + 1];
        int r2 = csr_row[i + 2];
        int r3 = csr_row[i + 3];
        union { short4 s4; _Float16 h[4]; } u0, u1, u2, u3;
        u0.s4 = xh4[((size_t)r0 << 4) + g];
        u1.s4 = xh4[((size_t)r1 << 4) + g];
        u2.s4 = xh4[((size_t)r2 << 4) + g];
        u3.s4 = xh4[((size_t)r3 << 4) + g];
        a0 += (float)u0.h[0] + (float)u1.h[0] + (float)u2.h[0] + (float)u3.h[0];
        a1 += (float)u0.h[1] + (float)u1.h[1] + (float)u2.h[1] + (float)u3.h[1];
        a2 += (float)u0.h[2] + (float)u1.h[2] + (float)u2.h[2] + (float)u3.h[2];
        a3 += (float)u0.h[3] + (float)u1.h[3] + (float)u2.h[3] + (float)u3.h[3];
    }
    for (; i < end; ++i) {
        int r = csr_row[i];
        union { short4 s4; _Float16 h[4]; } u;
        u.s4 = xh4[((size_t)r << 4) + g];
        a0 += (float)u.h[0]; a1 += (float)u.h[1];
        a2 += (float)u.h[2]; a3 += (float)u.h[3];
    }
    float dv = dinv[nd];
    ((float4*)x2)[((size_t)nd << 4) + g] = make_float4(dv * a0, dv * a1, dv * a2, dv * a3);
}

// ---------------- fused node-wise: fp16 LDS weights + dot2, 2-stage pipeline ----------
__global__ __launch_bounds__(512, 6) void fuse_kernel(
    const float* __restrict__ E, const float* __restrict__ E2,
    const float* __restrict__ W0, const float* __restrict__ b0,
    const float* __restrict__ W1, const float* __restrict__ b1,
    const float* __restrict__ AW, const float* __restrict__ ab,
    const float* __restrict__ qW,
    const _Float16* __restrict__ xn1, const float* __restrict__ sq,
    const float* x2, float* Z,
    const int* __restrict__ list, const int* __restrict__ count) {
    __shared__ __align__(16) _Float16 W0h[4096];   // quad-interleave: [(k>>2)*256 + j*4 + (k&3)]
    __shared__ __align__(16) _Float16 W1h[4096];
    __shared__ __align__(16) _Float16 AWh[4096];
    __shared__ float bb0[64], bb1[64], bab[64], qb[64];
    __shared__ __align__(16) _Float16 xb[8][64];
    __shared__ __align__(16) _Float16 hb[8][64];
    __shared__ __align__(16) _Float16 zpb[8][64];
    __shared__ __align__(16) _Float16 znb[8][64];

    int t = threadIdx.x;
    for (int idx = t; idx < 4096; idx += 512) {
        int j = idx >> 6, k = idx & 63;
        int dst = (k >> 2) * 256 + j * 4 + (k & 3);
        W0h[dst] = (_Float16)W0[idx];
        W1h[dst] = (_Float16)W1[idx];
        AWh[dst] = (_Float16)AW[idx];
    }
    if (t < 64) { bb0[t] = b0[t]; bb1[t] = b1[t]; bab[t] = ab[t]; qb[t] = qW[t]; }
    __syncthreads();   // weights staged once; node loop is wave-local

    const int lane = t & 63, w = t >> 6;
    const int cnt = *count;
    const int stride = gridDim.x * 8;
    int li = blockIdx.x * 8 + w;

    // pipeline stage A (current node's data in registers)
    int ndA = 0; float eA = 0.f, e2A = 0.f, x2A = 0.f, sqA = 0.f; _Float16 xnA = (_Float16)0.f;
    if (li < cnt) {
        ndA = list[li];
        size_t bA = ((size_t)ndA << 6) + lane;
        eA = E[bA]; e2A = E2[bA]; xnA = xn1[bA]; x2A = x2[bA]; sqA = sq[ndA];
    }

    for (; li < cnt; li += stride) {
        // issue next node's loads (stage B) — overlaps with current compute
        int liB = li + stride;
        int ndB = 0; float eB = 0.f, e2B = 0.f, x2B = 0.f, sqB = 0.f; _Float16 xnB = (_Float16)0.f;
        if (liB < cnt) {
            ndB = list[liB];
            size_t bB = ((size_t)ndB << 6) + lane;
            eB = E[bB]; e2B = E2[bB]; xnB = xn1[bB]; x2B = x2[bB]; sqB = sq[ndB];
        }

        size_t base = ((size_t)ndA << 6) + lane;
        float x1v = sqA * (float)xnA;
        float zp = (eA + x1v + x2A) * (1.f / 3.f);
        zpb[w][lane] = (_Float16)zp;
        xb[w][lane] = (_Float16)e2A;
        __builtin_amdgcn_wave_barrier();

        // h = relu(E2 @ W0.T + b0)
        float s0 = bb0[lane], s1 = 0.f;
#pragma unroll
        for (int k4 = 0; k4 < 16; k4++) {
            half4v w4 = *(const half4v*)&W0h[k4 * 256 + lane * 4];
            half4v x4 = *(const half4v*)&xb[w][k4 * 4];
            s0 = __builtin_amdgcn_fdot2((half2v){w4.x, w4.y}, (half2v){x4.x, x4.y}, s0, false);
            s1 = __builtin_amdgcn_fdot2((half2v){w4.z, w4.w}, (half2v){x4.z, x4.w}, s1, false);
        }
        float h = fmaxf(s0 + s1, 0.f);
        hb[w][lane] = (_Float16)h;
        __builtin_amdgcn_wave_barrier();

        // z_n = relu(h @ W1.T + b1)
        s0 = bb1[lane]; s1 = 0.f;
#pragma unroll
        for (int k4 = 0; k4 < 16; k4++) {
            half4v w4 = *(const half4v*)&W1h[k4 * 256 + lane * 4];
            half4v x4 = *(const half4v*)&hb[w][k4 * 4];
            s0 = __builtin_amdgcn_fdot2((half2v){w4.x, w4.y}, (half2v){x4.x, x4.y}, s0, false);
            s1 = __builtin_amdgcn_fdot2((half2v){w4.z, w4.w}, (half2v){x4.z, x4.w}, s1, false);
        }
        float zn = fmaxf(s0 + s1, 0.f);
        znb[w][lane] = (_Float16)zn;
        __builtin_amdgcn_wave_barrier();

        // attention scores for zp and zn (shared W read, 4 accumulators)
        float sp0 = bab[lane], sp1 = 0.f, sn0 = 0.f, sn1 = 0.f;
#pragma unroll
        for (int k4 = 0; k4 < 16; k4++) {
            half4v w4 = *(const half4v*)&AWh[k4 * 256 + lane * 4];
            half4v p4 = *(const half4v*)&zpb[w][k4 * 4];
            half4v n4 = *(const half4v*)&znb[w][k4 * 4];
            sp0 = __builtin_amdgcn_fdot2((half2v){w4.x, w4.y}, (half2v){p4.x, p4.y}, sp0, false);
            sp1 = __builtin_amdgcn_fdot2((half2v){w4.z, w4.w}, (half2v){p4.z, p4.w}, sp1, false);
            sn0 = __builtin_amdgcn_fdot2((half2v){w4.x, w4.y}, (half2v){n4.x, n4.y}, sn0, false);
            sn1 = __builtin_amdgcn_fdot2((half2v){w4.z, w4.w}, (half2v){n4.z, n4.w}, sn1, false);
        }
        float tp = tanhf(sp0 + sp1) * qb[lane];
        float tn = tanhf(bab[lane] + sn0 + sn1) * qb[lane];
        for (int m = 1; m < 64; m <<= 1) {
            tp += __shfl_xor(tp, m);
            tn += __shfl_xor(tn, m);
        }
        float mx = fmaxf(tp, tn);
        float ep = expf(tp - mx), en = expf(tn - mx);
        float inv = 1.f / (ep + en);
        Z[base] = (ep * zp + en * zn) * inv;
        __builtin_amdgcn_wave_barrier();

        // rotate pipeline
        ndA = ndB; eA = eB; e2A = e2B; xnA = xnB; x2A = x2B; sqA = sqB;
    }
}

// ---------------- loss ----------------
__global__ __launch_bounds__(256) void loss_kernel(const float* __restrict__ Z,
                                                   const float* __restrict__ wv,
                                                   const int* __restrict__ u,
                                                   const int* __restrict__ v,
                                                   const int* __restrict__ n,
                                                   float* __restrict__ out) {
    int wid = (blockIdx.x * blockDim.x + threadIdx.x) >> 6;
    int lane = threadIdx.x & 63;
    if (wid >= BATCH) return;
    float uu = Z[(size_t)u[wid] * DIM + lane];
    float vv = Z[(size_t)v[wid] * DIM + lane];
    float pos = uu * vv;
    for (int m = 1; m < 64; m <<= 1) pos += __shfl_xor(pos, m);
    float reg = uu * uu + vv * vv;
    float wval = wv[wid];
    float sgn = (wval > 0.f ? 1.f : 0.f) - (wval < 0.f ? 1.f : 0.f);
    float coef = -0.5f * sgn + 1.5f;
    float cp = coef * pos;
    float sb = 0.f;
    for (int k = 0; k < N_NEGS; k++) {
        int nid = n[wid * N_NEGS + k];
        float nn = Z[(size_t)nid * DIM + lane];
        float d = uu * nn;
        for (int m = 1; m < 64; m <<= 1) d += __shfl_xor(d, m);
        reg += nn * nn;
        float x = cp - d;
        float ls = (x >= 0.f) ? -log1pf(expf(-x)) : (x - log1pf(expf(x)));
        sb += ls;
    }
    for (int m = 1; m < 64; m <<= 1) reg += __shfl_xor(reg, m);
    if (lane == 0) atomicAdd(out, -sb + REG_COEF * reg);
}

extern "C" void kernel_launch(void* const* d_in, const int* in_sizes, int n_in,
                              void* d_out, int out_size, void* d_ws, size_t ws_size,
                              hipStream_t stream) {
    const float* E  = (const float*)d_in[0];
    const float* E2 = (const float*)d_in[1];
    const float* W0 = (const float*)d_in[2];
    const float* b0 = (const float*)d_in[3];
    const float* W1 = (const float*)d_in[4];
    const float* b1 = (const float*)d_in[5];
    const float* AW = (const float*)d_in[6];
    const float* ab = (const float*)d_in[7];
    const float* qW = (const float*)d_in[8];
    const float* wv = (const float*)d_in[9];
    const int* ei   = (const int*)d_in[10];
    const int* uu   = (const int*)d_in[11];
    const int* vv   = (const int*)d_in[12];
    const int* nn   = (const int*)d_in[13];
    const int* row = ei;
    const int* col = ei + N_EDGES;

    char* ws = (char*)d_ws;
    size_t p = 0;
    auto align_up = [](size_t x) { return (x + 255) & ~(size_t)255; };
    int* off        = (int*)(ws + p); p = align_up(p + (size_t)(NUM_NODES + 1) * 4);
    float* dinv     = (float*)(ws + p); p = align_up(p + (size_t)NUM_NODES * 4);
    float* sq       = (float*)(ws + p); p = align_up(p + (size_t)NUM_NODES * 4);
    int* hist       = (int*)(ws + p); p = align_up(p + (size_t)HSIZE * 4);
    int* partial    = (int*)(ws + p); p = align_up(p + (size_t)NB2 * 4);
    int* csr_row    = (int*)(ws + p); p = align_up(p + (size_t)N_EDGES * 4);
    char* flags     = (char*)(ws + p); p = align_up(p + (size_t)NUM_NODES);
    int* list       = (int*)(ws + p); p = align_up(p + (size_t)NLIST * 4);
    int* count      = (int*)(ws + p); p = align_up(p + 4);
    __hip_fp8x4_e4m3* xnE4 = (__hip_fp8x4_e4m3*)(ws + p); p = align_up(p + (size_t)NUM_NODES * DIM);
    _Float16* xn1   = (_Float16*)(ws + p); p = align_up(p + (size_t)NUM_NODES * DIM * 2);
    float* x2f      = (float*)(ws + p); p = align_up(p + (size_t)NUM_NODES * DIM * 4);
    float* Z = x2f;                      // alias: fuse reads x2f[nd] then writes Z[nd] same thread
    unsigned* staging = (unsigned*)x2f;  // alias: staging consumed by fill3 before conv2 writes x2f

    hipMemsetAsync(d_out, 0, sizeof(float), stream);
    hipMemsetAsync(flags, 0, (size_t)NUM_NODES, stream);
    hipMemsetAsync(count, 0, 4, stream);

    histo_kernel<<<NT, 256, 0, stream>>>(col, hist);
    scan_partial_kernel<<<NB2, SCAN_B, 0, stream>>>(hist, partial, HSIZE);
    scan_base_kernel<<<1, 64, 0, stream>>>(partial, NB2, 2);
    scan_apply_kernel<<<NB2, SCAN_B, 0, stream>>>(hist, partial, HSIZE);
    partition_kernel<<<NT, 256, 0, stream>>>(row, col, hist, staging);
    fill3_kernel<<<NBK, 512, 0, stream>>>(hist, staging, E, off, dinv, sq, csr_row, xnE4);

    flag_kernel<<<(NLIST + 255) / 256, 256, 0, stream>>>(uu, vv, nn, flags);
    compact_kernel<<<(NUM_NODES + 255) / 256, 256, 0, stream>>>(flags, list, count);

    conv1_kernel<<<(NUM_NODES * 16 + 255) / 256, 256, 0, stream>>>(off, csr_row, dinv, xnE4, xn1);
    conv2_kernel<<<(NLIST * 16 + 255) / 256, 256, 0, stream>>>(off, csr_row, dinv, xn1, x2f, list, count);

    fuse_kernel<<<1024, 512, 0, stream>>>(E, E2, W0, b0, W1, b1, AW, ab, qW,
                                          xn1, sq, x2f, Z, list, count);

    loss_kernel<<<BATCH * 64 / 256, 256, 0, stream>>>(Z, wv, uu, vv, nn, (float*)d_out);
}

// Round 9
// 296.088 us; speedup vs baseline: 1.1021x; 1.1021x over previous
//
#include <hip/hip_runtime.h>
#include <hip/hip_fp8.h>
#include <math.h>

#define NUM_NODES 150000
#define DIM 64
#define N_EDGES 3200000
#define BATCH 1024
#define N_NEGS 40
#define REG_COEF 1e-4f

#define BK_BITS 9
#define BK_NODES 512
#define NBK ((NUM_NODES + BK_NODES - 1) >> BK_BITS)      // 293
#define TILE 8192
#define NT ((N_EDGES + TILE - 1) / TILE)                 // 391
#define HSIZE (NBK * NT)                                 // 114563
#define SCAN_B 1024
#define NB2 ((HSIZE + SCAN_B - 1) / SCAN_B)              // 112
#define NLIST (BATCH * (N_NEGS + 2))                     // 43008

typedef _Float16 half2v __attribute__((ext_vector_type(2)));
typedef _Float16 half4v __attribute__((ext_vector_type(4)));

// ---------------- pass 1: per-tile bucket histogram ----------------
__global__ __launch_bounds__(256) void histo_kernel(const int* __restrict__ col,
                                                    int* __restrict__ hist) {
    __shared__ int h[NBK];
    int t = threadIdx.x;
    for (int i = t; i < NBK; i += 256) h[i] = 0;
    __syncthreads();
    int e0 = blockIdx.x * TILE;
    int e1 = e0 + TILE; if (e1 > N_EDGES) e1 = N_EDGES;
    for (int i = e0 + t; i < e1; i += 256) atomicAdd(&h[col[i] >> BK_BITS], 1);
    __syncthreads();
    for (int i = t; i < NBK; i += 256) hist[i * NT + blockIdx.x] = h[i];
}

// ---------------- scan (3 kernels) over hist[HSIZE] -> exclusive in-place ----------------
__global__ void scan_partial_kernel(const int* __restrict__ src, int* __restrict__ partial, int n) {
    int t = threadIdx.x;
    int g = blockIdx.x * SCAN_B + t;
    int v = (g < n) ? src[g] : 0;
    for (int m = 1; m < 64; m <<= 1) v += __shfl_xor(v, m);
    __shared__ int ws[16];
    if ((t & 63) == 0) ws[t >> 6] = v;
    __syncthreads();
    if (t < 16) {
        int s = ws[t];
        for (int m = 1; m < 16; m <<= 1) s += __shfl_xor(s, m);
        if (t == 0) partial[blockIdx.x] = s;
    }
}

__global__ void scan_base_kernel(int* __restrict__ partial, int nb, int chunks) {
    int l = threadIdx.x;
    int carry = 0;
    for (int c = 0; c < chunks; c++) {
        int idx = c * 64 + l;
        int v = (idx < nb) ? partial[idx] : 0;
        int inc = v;
        for (int m = 1; m < 64; m <<= 1) {
            int t = __shfl_up(inc, m);
            if (l >= m) inc += t;
        }
        int excl = inc - v + carry;
        if (idx < nb) partial[idx] = excl;
        carry += __shfl(inc, 63);
    }
}

__global__ void scan_apply_kernel(int* __restrict__ data, const int* __restrict__ partial, int n) {
    __shared__ int lds[SCAN_B];
    int t = threadIdx.x;
    int g = blockIdx.x * SCAN_B + t;
    int v = (g < n) ? data[g] : 0;
    int val = v;
    lds[t] = val;
    __syncthreads();
    for (int o = 1; o < SCAN_B; o <<= 1) {
        int add = (t >= o) ? lds[t - o] : 0;
        __syncthreads();
        val += add;
        lds[t] = val;
        __syncthreads();
    }
    if (g < n) data[g] = partial[blockIdx.x] + val - v;  // exclusive
}

// ---------------- pass 2: rank-based partition into bucket-grouped staging ----------------
__global__ __launch_bounds__(256) void partition_kernel(const int* __restrict__ row,
                                                        const int* __restrict__ col,
                                                        const int* __restrict__ hist,
                                                        unsigned* __restrict__ staging) {
    __shared__ int base[NBK];
    __shared__ int cnt[NBK];
    int t = threadIdx.x;
    for (int i = t; i < NBK; i += 256) { base[i] = hist[i * NT + blockIdx.x]; cnt[i] = 0; }
    __syncthreads();
    int e0 = blockIdx.x * TILE;
    int e1 = e0 + TILE; if (e1 > N_EDGES) e1 = N_EDGES;
    for (int i = e0 + t; i < e1; i += 256) {
        int c = col[i];
        int b = c >> BK_BITS;
        int r = atomicAdd(&cnt[b], 1);
        staging[base[b] + r] = ((unsigned)(c & (BK_NODES - 1)) << 18) | (unsigned)row[i];
    }
}

// ------ pass 3: per-bucket offsets + dinv + sq + CSR + pre-scaled fp8 E (x16 scale) ------
__global__ __launch_bounds__(512) void fill3_kernel(const int* __restrict__ hist,
                                                    const unsigned* __restrict__ staging,
                                                    const float* __restrict__ E,
                                                    int* __restrict__ off,
                                                    float* __restrict__ dinv,
                                                    float* __restrict__ sq,
                                                    int* __restrict__ csr_row,
                                                    __hip_fp8x4_e4m3* __restrict__ xnE4) {
    __shared__ int cnt[BK_NODES];
    __shared__ int lds[BK_NODES];
    __shared__ float sdinv[BK_NODES];
    int b = blockIdx.x;
    int t = threadIdx.x;
    int node0 = b << BK_BITS;
    int bstart = hist[b * NT];
    int bend = (b + 1 < NBK) ? hist[(b + 1) * NT] : N_EDGES;
    cnt[t] = 0;
    __syncthreads();
    for (int i = bstart + t; i < bend; i += 512) atomicAdd(&cnt[staging[i] >> 18], 1);
    __syncthreads();
    int v = cnt[t];
    int val = v;
    lds[t] = val;
    __syncthreads();
    for (int o = 1; o < BK_NODES; o <<= 1) {
        int add = (t >= o) ? lds[t - o] : 0;
        __syncthreads();
        val += add;
        lds[t] = val;
        __syncthreads();
    }
    int cursor = bstart + val - v;   // exclusive
    int node = node0 + t;
    float dv = (v > 0) ? rsqrtf((float)v) : 0.f;
    if (node < NUM_NODES) {
        off[node] = cursor;
        dinv[node] = dv;
        sq[node] = sqrtf((float)v);
    }
    sdinv[t] = dv;
    cnt[t] = cursor;
    __syncthreads();
    for (int i = bstart + t; i < bend; i += 512) {
        unsigned s = staging[i];
        int pos = atomicAdd(&cnt[s >> 18], 1);
        csr_row[pos] = (int)(s & 0x3FFFFu);
    }
    // pre-scaled fp8 operand: xnE[node] = e4m3( 16 * dinv[node] * E[node] )
    int nvalid = NUM_NODES - node0; if (nvalid > BK_NODES) nvalid = BK_NODES;
    int groups = nvalid << 4;                         // 16 float4-groups per row
    const float4* E4 = (const float4*)E + ((size_t)node0 << 4);
    __hip_fp8x4_e4m3* out4 = xnE4 + ((size_t)node0 << 4);
    for (int gi = t; gi < groups; gi += 512) {
        float4 e = E4[gi];
        float s = 16.f * sdinv[gi >> 4];
        out4[gi] = __hip_fp8x4_e4m3(make_float4(s * e.x, s * e.y, s * e.z, s * e.w));
    }
    if (b == 0 && t == 0) off[NUM_NODES] = N_EDGES;
}

// ---------------- mark + compact the ~39K nodes the loss actually touches ------------
__global__ void flag_kernel(const int* __restrict__ u, const int* __restrict__ v,
                            const int* __restrict__ n, char* __restrict__ flags) {
    int i = blockIdx.x * blockDim.x + threadIdx.x;
    if (i >= NLIST) return;
    int id;
    if (i < BATCH) id = u[i];
    else if (i < 2 * BATCH) id = v[i - BATCH];
    else id = n[i - 2 * BATCH];
    flags[id] = 1;
}

__global__ void compact_kernel(const char* __restrict__ flags, int* __restrict__ list,
                               int* __restrict__ count) {
    int i = blockIdx.x * blockDim.x + threadIdx.x;
    if (i < NUM_NODES && flags[i]) {
        int pos = atomicAdd(count, 1);
        list[pos] = i;
    }
}

// ---- conv layer 1 (full graph, fp8 operand, one 16-lane group per node) ----
__global__ __launch_bounds__(256) void conv1_kernel(const int* __restrict__ off,
                                                    const int* __restrict__ csr_row,
                                                    const float* __restrict__ dinv,
                                                    const __hip_fp8x4_e4m3* __restrict__ xq,
                                                    _Float16* __restrict__ yh) {
    int gid = blockIdx.x * blockDim.x + threadIdx.x;
    int grp = gid >> 4;               // node index
    int g = threadIdx.x & 15;         // dim group
    if (grp >= NUM_NODES) return;
    int start = off[grp];
    int end = off[grp + 1];
    float a0 = 0.f, a1 = 0.f, a2 = 0.f, a3 = 0.f;
    int i = start;
    for (; i + 3 < end; i += 4) {
        int r0 = csr_row[i];
        int r1 = csr_row[i + 1];
        int r2 = csr_row[i + 2];
        int r3 = csr_row[i + 3];
        float4 v0 = static_cast<float4>(xq[((size_t)r0 << 4) + g]);
        float4 v1 = static_cast<float4>(xq[((size_t)r1 << 4) + g]);
        float4 v2 = static_cast<float4>(xq[((size_t)r2 << 4) + g]);
        float4 v3 = static_cast<float4>(xq[((size_t)r3 << 4) + g]);
        a0 += v0.x + v1.x + v2.x + v3.x;
        a1 += v0.y + v1.y + v2.y + v3.y;
        a2 += v0.z + v1.z + v2.z + v3.z;
        a3 += v0.w + v1.w + v2.w + v3.w;
    }
    for (; i < end; ++i) {
        int r = csr_row[i];
        float4 v = static_cast<float4>(xq[((size_t)r << 4) + g]);
        a0 += v.x; a1 += v.y; a2 += v.z; a3 += v.w;
    }
    float dv = dinv[grp];
    float s = dv * dv * (1.f / 16.f);
    union { _Float16 h[4]; short4 s4; } u;
    u.h[0] = (_Float16)(s * a0);
    u.h[1] = (_Float16)(s * a1);
    u.h[2] = (_Float16)(s * a2);
    u.h[3] = (_Float16)(s * a3);
    ((short4*)yh)[((size_t)grp << 4) + g] = u.s4;
}

// ---- conv layer 2 (listed nodes, fp16 operand, one 16-lane group per node) ----
__global__ __launch_bounds__(256) void conv2_kernel(const int* __restrict__ off,
                                                    const int* __restrict__ csr_row,
                                                    const float* __restrict__ dinv,
                                                    const _Float16* __restrict__ xh,
                                                    float* __restrict__ x2,
                                                    const int* __restrict__ list,
                                                    const int* __restrict__ count) {
    int gid = blockIdx.x * blockDim.x + threadIdx.x;
    int li = gid >> 4;
    int g = threadIdx.x & 15;
    if (li >= *count) return;
    int nd = list[li];
    int start = off[nd];
    int end = off[nd + 1];
    const short4* xh4 = (const short4*)xh;
    float a0 = 0.f, a1 = 0.f, a2 = 0.f, a3 = 0.f;
    int i = start;
    for (; i + 3 < end; i += 4) {
        int r0 = csr_row[i];
        int r1 = csr_row[i + 1];
        int r2 = csr_row[i + 2];
        int r3 = csr_row[i + 3];
        union { short4 s4; _Float16 h[4]; } u0, u1, u2, u3;
        u0.s4 = xh4[((size_t)r0 << 4) + g];
        u1.s4 = xh4[((size_t)r1 << 4) + g];
        u2.s4 = xh4[((size_t)r2 << 4) + g];
        u3.s4 = xh4[((size_t)r3 << 4) + g];
        a0 += (float)u0.h[0] + (float)u1.h[0] + (float)u2.h[0] + (float)u3.h[0];
        a1 += (float)u0.h[1] + (float)u1.h[1] + (float)u2.h[1] + (float)u3.h[1];
        a2 += (float)u0.h[2] + (float)u1.h[2] + (float)u2.h[2] + (float)u3.h[2];
        a3 += (float)u0.h[3] + (float)u1.h[3] + (float)u2.h[3] + (float)u3.h[3];
    }
    for (; i < end; ++i) {
        int r = csr_row[i];
        union { short4 s4; _Float16 h[4]; } u;
        u.s4 = xh4[((size_t)r << 4) + g];
        a0 += (float)u.h[0]; a1 += (float)u.h[1];
        a2 += (float)u.h[2]; a3 += (float)u.h[3];
    }
    float dv = dinv[nd];
    ((float4*)x2)[((size_t)nd << 4) + g] = make_float4(dv * a0, dv * a1, dv * a2, dv * a3);
}

// -------- fused node-wise: fp16 LDS weights + dot2, 256-thr blocks, 5 blocks/CU --------
__global__ __launch_bounds__(256, 5) void fuse_kernel(
    const float* __restrict__ E, const float* __restrict__ E2,
    const float* __restrict__ W0, const float* __restrict__ b0,
    const float* __restrict__ W1, const float* __restrict__ b1,
    const float* __restrict__ AW, const float* __restrict__ ab,
    const float* __restrict__ qW,
    const _Float16* __restrict__ xn1, const float* __restrict__ sq,
    const float* x2, float* Z,
    const int* __restrict__ list, const int* __restrict__ count) {
    __shared__ __align__(16) _Float16 W0h[4096];   // quad-interleave: [(k>>2)*256 + j*4 + (k&3)]
    __shared__ __align__(16) _Float16 W1h[4096];
    __shared__ __align__(16) _Float16 AWh[4096];
    __shared__ float bb0[64], bb1[64], bab[64], qb[64];
    __shared__ __align__(16) _Float16 xb[4][64];
    __shared__ __align__(16) _Float16 hb[4][64];
    __shared__ __align__(16) _Float16 zpb[4][64];
    __shared__ __align__(16) _Float16 znb[4][64];

    int t = threadIdx.x;
    for (int idx = t; idx < 4096; idx += 256) {
        int j = idx >> 6, k = idx & 63;
        int dst = (k >> 2) * 256 + j * 4 + (k & 3);
        W0h[dst] = (_Float16)W0[idx];
        W1h[dst] = (_Float16)W1[idx];
        AWh[dst] = (_Float16)AW[idx];
    }
    if (t < 64) { bb0[t] = b0[t]; bb1[t] = b1[t]; bab[t] = ab[t]; qb[t] = qW[t]; }
    __syncthreads();   // weights staged once; node loop is wave-local

    const int lane = t & 63, w = t >> 6;
    const int cnt = *count;
    const int stride = gridDim.x * 4;
    int li = blockIdx.x * 4 + w;

    // pipeline stage A (current node's data in registers)
    int ndA = 0; float eA = 0.f, e2A = 0.f, x2A = 0.f, sqA = 0.f; _Float16 xnA = (_Float16)0.f;
    if (li < cnt) {
        ndA = list[li];
        size_t bA = ((size_t)ndA << 6) + lane;
        eA = E[bA]; e2A = E2[bA]; xnA = xn1[bA]; x2A = x2[bA]; sqA = sq[ndA];
    }

    for (; li < cnt; li += stride) {
        // issue next node's loads (stage B) — overlaps with current compute
        int liB = li + stride;
        int ndB = 0; float eB = 0.f, e2B = 0.f, x2B = 0.f, sqB = 0.f; _Float16 xnB = (_Float16)0.f;
        if (liB < cnt) {
            ndB = list[liB];
            size_t bB = ((size_t)ndB << 6) + lane;
            eB = E[bB]; e2B = E2[bB]; xnB = xn1[bB]; x2B = x2[bB]; sqB = sq[ndB];
        }

        size_t base = ((size_t)ndA << 6) + lane;
        float x1v = sqA * (float)xnA;
        float zp = (eA + x1v + x2A) * (1.f / 3.f);
        zpb[w][lane] = (_Float16)zp;
        xb[w][lane] = (_Float16)e2A;
        __builtin_amdgcn_wave_barrier();

        // h = relu(E2 @ W0.T + b0)
        float s0 = bb0[lane], s1 = 0.f;
#pragma unroll
        for (int k4 = 0; k4 < 16; k4++) {
            half4v w4 = *(const half4v*)&W0h[k4 * 256 + lane * 4];
            half4v x4 = *(const half4v*)&xb[w][k4 * 4];
            s0 = __builtin_amdgcn_fdot2((half2v){w4.x, w4.y}, (half2v){x4.x, x4.y}, s0, false);
            s1 = __builtin_amdgcn_fdot2((half2v){w4.z, w4.w}, (half2v){x4.z, x4.w}, s1, false);
        }
        float h = fmaxf(s0 + s1, 0.f);
        hb[w][lane] = (_Float16)h;
        __builtin_amdgcn_wave_barrier();

        // z_n = relu(h @ W1.T + b1)
        s0 = bb1[lane]; s1 = 0.f;
#pragma unroll
        for (int k4 = 0; k4 < 16; k4++) {
            half4v w4 = *(const half4v*)&W1h[k4 * 256 + lane * 4];
            half4v x4 = *(const half4v*)&hb[w][k4 * 4];
            s0 = __builtin_amdgcn_fdot2((half2v){w4.x, w4.y}, (half2v){x4.x, x4.y}, s0, false);
            s1 = __builtin_amdgcn_fdot2((half2v){w4.z, w4.w}, (half2v){x4.z, x4.w}, s1, false);
        }
        float zn = fmaxf(s0 + s1, 0.f);
        znb[w][lane] = (_Float16)zn;
        __builtin_amdgcn_wave_barrier();

        // attention scores for zp and zn (shared W read, 4 accumulators)
        float sp0 = bab[lane], sp1 = 0.f, sn0 = 0.f, sn1 = 0.f;
#pragma unroll
        for (int k4 = 0; k4 < 16; k4++) {
            half4v w4 = *(const half4v*)&AWh[k4 * 256 + lane * 4];
            half4v p4 = *(const half4v*)&zpb[w][k4 * 4];
            half4v n4 = *(const half4v*)&znb[w][k4 * 4];
            sp0 = __builtin_amdgcn_fdot2((half2v){w4.x, w4.y}, (half2v){p4.x, p4.y}, sp0, false);
            sp1 = __builtin_amdgcn_fdot2((half2v){w4.z, w4.w}, (half2v){p4.z, p4.w}, sp1, false);
            sn0 = __builtin_amdgcn_fdot2((half2v){w4.x, w4.y}, (half2v){n4.x, n4.y}, sn0, false);
            sn1 = __builtin_amdgcn_fdot2((half2v){w4.z, w4.w}, (half2v){n4.z, n4.w}, sn1, false);
        }
        float tp = tanhf(sp0 + sp1) * qb[lane];
        float tn = tanhf(bab[lane] + sn0 + sn1) * qb[lane];
        for (int m = 1; m < 64; m <<= 1) {
            tp += __shfl_xor(tp, m);
            tn += __shfl_xor(tn, m);
        }
        float mx = fmaxf(tp, tn);
        float ep = expf(tp - mx), en = expf(tn - mx);
        float inv = 1.f / (ep + en);
        Z[base] = (ep * zp + en * zn) * inv;
        __builtin_amdgcn_wave_barrier();

        // rotate pipeline
        ndA = ndB; eA = eB; e2A = e2B; xnA = xnB; x2A = x2B; sqA = sqB;
    }
}

// ---------------- loss ----------------
__global__ __launch_bounds__(256) void loss_kernel(const float* __restrict__ Z,
                                                   const float* __restrict__ wv,
                                                   const int* __restrict__ u,
                                                   const int* __restrict__ v,
                                                   const int* __restrict__ n,
                                                   float* __restrict__ out) {
    int wid = (blockIdx.x * blockDim.x + threadIdx.x) >> 6;
    int lane = threadIdx.x & 63;
    if (wid >= BATCH) return;
    float uu = Z[(size_t)u[wid] * DIM + lane];
    float vv = Z[(size_t)v[wid] * DIM + lane];
    float pos = uu * vv;
    for (int m = 1; m < 64; m <<= 1) pos += __shfl_xor(pos, m);
    float reg = uu * uu + vv * vv;
    float wval = wv[wid];
    float sgn = (wval > 0.f ? 1.f : 0.f) - (wval < 0.f ? 1.f : 0.f);
    float coef = -0.5f * sgn + 1.5f;
    float cp = coef * pos;
    float sb = 0.f;
    for (int k = 0; k < N_NEGS; k++) {
        int nid = n[wid * N_NEGS + k];
        float nn = Z[(size_t)nid * DIM + lane];
        float d = uu * nn;
        for (int m = 1; m < 64; m <<= 1) d += __shfl_xor(d, m);
        reg += nn * nn;
        float x = cp - d;
        float ls = (x >= 0.f) ? -log1pf(expf(-x)) : (x - log1pf(expf(x)));
        sb += ls;
    }
    for (int m = 1; m < 64; m <<= 1) reg += __shfl_xor(reg, m);
    if (lane == 0) atomicAdd(out, -sb + REG_COEF * reg);
}

extern "C" void kernel_launch(void* const* d_in, const int* in_sizes, int n_in,
                              void* d_out, int out_size, void* d_ws, size_t ws_size,
                              hipStream_t stream) {
    const float* E  = (const float*)d_in[0];
    const float* E2 = (const float*)d_in[1];
    const float* W0 = (const float*)d_in[2];
    const float* b0 = (const float*)d_in[3];
    const float* W1 = (const float*)d_in[4];
    const float* b1 = (const float*)d_in[5];
    const float* AW = (const float*)d_in[6];
    const float* ab = (const float*)d_in[7];
    const float* qW = (const float*)d_in[8];
    const float* wv = (const float*)d_in[9];
    const int* ei   = (const int*)d_in[10];
    const int* uu   = (const int*)d_in[11];
    const int* vv   = (const int*)d_in[12];
    const int* nn   = (const int*)d_in[13];
    const int* row = ei;
    const int* col = ei + N_EDGES;

    char* ws = (char*)d_ws;
    size_t p = 0;
    auto align_up = [](size_t x) { return (x + 255) & ~(size_t)255; };
    int* off        = (int*)(ws + p); p = align_up(p + (size_t)(NUM_NODES + 1) * 4);
    float* dinv     = (float*)(ws + p); p = align_up(p + (size_t)NUM_NODES * 4);
    float* sq       = (float*)(ws + p); p = align_up(p + (size_t)NUM_NODES * 4);
    int* hist       = (int*)(ws + p); p = align_up(p + (size_t)HSIZE * 4);
    int* partial    = (int*)(ws + p); p = align_up(p + (size_t)NB2 * 4);
    int* csr_row    = (int*)(ws + p); p = align_up(p + (size_t)N_EDGES * 4);
    char* flags     = (char*)(ws + p); p = align_up(p + (size_t)NUM_NODES);
    int* list       = (int*)(ws + p); p = align_up(p + (size_t)NLIST * 4);
    int* count      = (int*)(ws + p); p = align_up(p + 4);
    __hip_fp8x4_e4m3* xnE4 = (__hip_fp8x4_e4m3*)(ws + p); p = align_up(p + (size_t)NUM_NODES * DIM);
    _Float16* xn1   = (_Float16*)(ws + p); p = align_up(p + (size_t)NUM_NODES * DIM * 2);
    float* x2f      = (float*)(ws + p); p = align_up(p + (size_t)NUM_NODES * DIM * 4);
    float* Z = x2f;                      // alias: fuse reads x2f[nd] then writes Z[nd] same thread
    unsigned* staging = (unsigned*)x2f;  // alias: staging consumed by fill3 before conv2 writes x2f

    hipMemsetAsync(d_out, 0, sizeof(float), stream);
    hipMemsetAsync(flags, 0, (size_t)NUM_NODES, stream);
    hipMemsetAsync(count, 0, 4, stream);

    histo_kernel<<<NT, 256, 0, stream>>>(col, hist);
    scan_partial_kernel<<<NB2, SCAN_B, 0, stream>>>(hist, partial, HSIZE);
    scan_base_kernel<<<1, 64, 0, stream>>>(partial, NB2, 2);
    scan_apply_kernel<<<NB2, SCAN_B, 0, stream>>>(hist, partial, HSIZE);
    partition_kernel<<<NT, 256, 0, stream>>>(row, col, hist, staging);
    fill3_kernel<<<NBK, 512, 0, stream>>>(hist, staging, E, off, dinv, sq, csr_row, xnE4);

    flag_kernel<<<(NLIST + 255) / 256, 256, 0, stream>>>(uu, vv, nn, flags);
    compact_kernel<<<(NUM_NODES + 255) / 256, 256, 0, stream>>>(flags, list, count);

    conv1_kernel<<<(NUM_NODES * 16 + 255) / 256, 256, 0, stream>>>(off, csr_row, dinv, xnE4, xn1);
    conv2_kernel<<<(NLIST * 16 + 255) / 256, 256, 0, stream>>>(off, csr_row, dinv, xn1, x2f, list, count);

    fuse_kernel<<<1280, 256, 0, stream>>>(E, E2, W0, b0, W1, b1, AW, ab, qW,
                                          xn1, sq, x2f, Z, list, count);

    loss_kernel<<<BATCH * 64 / 256, 256, 0, stream>>>(Z, wv, uu, vv, nn, (float*)d_out);
}

// Round 10
// 270.454 us; speedup vs baseline: 1.2065x; 1.0948x over previous
//
#include <hip/hip_runtime.h>
#include <hip/hip_fp8.h>
#include <math.h>

#define NUM_NODES 150000
#define DIM 64
#define N_EDGES 3200000
#define BATCH 1024
#define N_NEGS 40
#define REG_COEF 1e-4f

#define BK_BITS 9
#define BK_NODES 512
#define NBK ((NUM_NODES + BK_NODES - 1) >> BK_BITS)      // 293
#define TILE 8192
#define NT ((N_EDGES + TILE - 1) / TILE)                 // 391
#define HSIZE (NBK * NT)                                 // 114563
#define SCAN_B 1024
#define NB2 ((HSIZE + SCAN_B - 1) / SCAN_B)              // 112
#define NB3 ((NUM_NODES + SCAN_B - 1) / SCAN_B)          // 147
#define NLIST (BATCH * (N_NEGS + 2))                     // 43008

typedef _Float16 half2v __attribute__((ext_vector_type(2)));
typedef _Float16 half4v __attribute__((ext_vector_type(4)));

// ---------------- pass 1: per-tile bucket histogram ----------------
__global__ __launch_bounds__(256) void histo_kernel(const int* __restrict__ col,
                                                    int* __restrict__ hist) {
    __shared__ int h[NBK];
    int t = threadIdx.x;
    for (int i = t; i < NBK; i += 256) h[i] = 0;
    __syncthreads();
    int e0 = blockIdx.x * TILE;
    int e1 = e0 + TILE; if (e1 > N_EDGES) e1 = N_EDGES;
    for (int i = e0 + t; i < e1; i += 256) atomicAdd(&h[col[i] >> BK_BITS], 1);
    __syncthreads();
    for (int i = t; i < NBK; i += 256) hist[i * NT + blockIdx.x] = h[i];
}

// ---------------- scan (3 kernels), reusable ----------------
__global__ void scan_partial_kernel(const int* __restrict__ src, int* __restrict__ partial, int n) {
    int t = threadIdx.x;
    int g = blockIdx.x * SCAN_B + t;
    int v = (g < n) ? src[g] : 0;
    for (int m = 1; m < 64; m <<= 1) v += __shfl_xor(v, m);
    __shared__ int ws[16];
    if ((t & 63) == 0) ws[t >> 6] = v;
    __syncthreads();
    if (t < 16) {
        int s = ws[t];
        for (int m = 1; m < 16; m <<= 1) s += __shfl_xor(s, m);
        if (t == 0) partial[blockIdx.x] = s;
    }
}

__global__ void scan_base_kernel(int* __restrict__ partial, int nb, int chunks) {
    int l = threadIdx.x;
    int carry = 0;
    for (int c = 0; c < chunks; c++) {
        int idx = c * 64 + l;
        int v = (idx < nb) ? partial[idx] : 0;
        int inc = v;
        for (int m = 1; m < 64; m <<= 1) {
            int t = __shfl_up(inc, m);
            if (l >= m) inc += t;
        }
        int excl = inc - v + carry;
        if (idx < nb) partial[idx] = excl;
        carry += __shfl(inc, 63);
    }
}

// in-place exclusive scan (used for hist)
__global__ void scan_apply_kernel(int* __restrict__ data, const int* __restrict__ partial, int n) {
    __shared__ int lds[SCAN_B];
    int t = threadIdx.x;
    int g = blockIdx.x * SCAN_B + t;
    int v = (g < n) ? data[g] : 0;
    int val = v;
    lds[t] = val;
    __syncthreads();
    for (int o = 1; o < SCAN_B; o <<= 1) {
        int add = (t >= o) ? lds[t - o] : 0;
        __syncthreads();
        val += add;
        lds[t] = val;
        __syncthreads();
    }
    if (g < n) data[g] = partial[blockIdx.x] + val - v;  // exclusive
}

// out-of-place exclusive scan (src preserved; used for flags -> positions)
__global__ void scan_apply2_kernel(const int* __restrict__ src, int* __restrict__ dst,
                                   const int* __restrict__ partial, int n) {
    __shared__ int lds[SCAN_B];
    int t = threadIdx.x;
    int g = blockIdx.x * SCAN_B + t;
    int v = (g < n) ? src[g] : 0;
    int val = v;
    lds[t] = val;
    __syncthreads();
    for (int o = 1; o < SCAN_B; o <<= 1) {
        int add = (t >= o) ? lds[t - o] : 0;
        __syncthreads();
        val += add;
        lds[t] = val;
        __syncthreads();
    }
    if (g < n) dst[g] = partial[blockIdx.x] + val - v;  // exclusive
}

// ---------------- pass 2: rank-based partition into bucket-grouped staging ----------------
__global__ __launch_bounds__(256) void partition_kernel(const int* __restrict__ row,
                                                        const int* __restrict__ col,
                                                        const int* __restrict__ hist,
                                                        unsigned* __restrict__ staging) {
    __shared__ int base[NBK];
    __shared__ int cnt[NBK];
    int t = threadIdx.x;
    for (int i = t; i < NBK; i += 256) { base[i] = hist[i * NT + blockIdx.x]; cnt[i] = 0; }
    __syncthreads();
    int e0 = blockIdx.x * TILE;
    int e1 = e0 + TILE; if (e1 > N_EDGES) e1 = N_EDGES;
    for (int i = e0 + t; i < e1; i += 256) {
        int c = col[i];
        int b = c >> BK_BITS;
        int r = atomicAdd(&cnt[b], 1);
        staging[base[b] + r] = ((unsigned)(c & (BK_NODES - 1)) << 18) | (unsigned)row[i];
    }
}

// ------ pass 3: per-bucket offsets + dinv + sq + CSR + pre-scaled fp8 E (x16 scale) ------
__global__ __launch_bounds__(512) void fill3_kernel(const int* __restrict__ hist,
                                                    const unsigned* __restrict__ staging,
                                                    const float* __restrict__ E,
                                                    int* __restrict__ off,
                                                    float* __restrict__ dinv,
                                                    float* __restrict__ sq,
                                                    int* __restrict__ csr_row,
                                                    __hip_fp8x4_e4m3* __restrict__ xnE4) {
    __shared__ int cnt[BK_NODES];
    __shared__ int lds[BK_NODES];
    __shared__ float sdinv[BK_NODES];
    int b = blockIdx.x;
    int t = threadIdx.x;
    int node0 = b << BK_BITS;
    int bstart = hist[b * NT];
    int bend = (b + 1 < NBK) ? hist[(b + 1) * NT] : N_EDGES;
    cnt[t] = 0;
    __syncthreads();
    for (int i = bstart + t; i < bend; i += 512) atomicAdd(&cnt[staging[i] >> 18], 1);
    __syncthreads();
    int v = cnt[t];
    int val = v;
    lds[t] = val;
    __syncthreads();
    for (int o = 1; o < BK_NODES; o <<= 1) {
        int add = (t >= o) ? lds[t - o] : 0;
        __syncthreads();
        val += add;
        lds[t] = val;
        __syncthreads();
    }
    int cursor = bstart + val - v;   // exclusive
    int node = node0 + t;
    float dv = (v > 0) ? rsqrtf((float)v) : 0.f;
    if (node < NUM_NODES) {
        off[node] = cursor;
        dinv[node] = dv;
        sq[node] = sqrtf((float)v);
    }
    sdinv[t] = dv;
    cnt[t] = cursor;
    __syncthreads();
    for (int i = bstart + t; i < bend; i += 512) {
        unsigned s = staging[i];
        int pos = atomicAdd(&cnt[s >> 18], 1);
        csr_row[pos] = (int)(s & 0x3FFFFu);
    }
    // pre-scaled fp8 operand: xnE[node] = e4m3( 16 * dinv[node] * E[node] )
    int nvalid = NUM_NODES - node0; if (nvalid > BK_NODES) nvalid = BK_NODES;
    int groups = nvalid << 4;                         // 16 float4-groups per row
    const float4* E4 = (const float4*)E + ((size_t)node0 << 4);
    __hip_fp8x4_e4m3* out4 = xnE4 + ((size_t)node0 << 4);
    for (int gi = t; gi < groups; gi += 512) {
        float4 e = E4[gi];
        float s = 16.f * sdinv[gi >> 4];
        out4[gi] = __hip_fp8x4_e4m3(make_float4(s * e.x, s * e.y, s * e.z, s * e.w));
    }
    if (b == 0 && t == 0) off[NUM_NODES] = N_EDGES;
}

// ---------------- mark (int flags) + ordered emit via scan positions ------------
__global__ void flag_kernel(const int* __restrict__ u, const int* __restrict__ v,
                            const int* __restrict__ n, int* __restrict__ flags) {
    int i = blockIdx.x * blockDim.x + threadIdx.x;
    if (i >= NLIST) return;
    int id;
    if (i < BATCH) id = u[i];
    else if (i < 2 * BATCH) id = v[i - BATCH];
    else id = n[i - 2 * BATCH];
    flags[id] = 1;
}

__global__ void emit_list_kernel(const int* __restrict__ flags, const int* __restrict__ posb,
                                 int* __restrict__ list, int* __restrict__ count) {
    int i = blockIdx.x * blockDim.x + threadIdx.x;
    if (i >= NUM_NODES) return;
    if (flags[i]) list[posb[i]] = i;            // sorted ascending by construction
    if (i == NUM_NODES - 1) *count = posb[i] + flags[i];
}

// ---- conv layer 1 (full graph, fp8 operand, one 16-lane group per node) ----
__global__ __launch_bounds__(256) void conv1_kernel(const int* __restrict__ off,
                                                    const int* __restrict__ csr_row,
                                                    const float* __restrict__ dinv,
                                                    const __hip_fp8x4_e4m3* __restrict__ xq,
                                                    _Float16* __restrict__ yh) {
    int gid = blockIdx.x * blockDim.x + threadIdx.x;
    int grp = gid >> 4;               // node index
    int g = threadIdx.x & 15;         // dim group
    if (grp >= NUM_NODES) return;
    int start = off[grp];
    int end = off[grp + 1];
    float a0 = 0.f, a1 = 0.f, a2 = 0.f, a3 = 0.f;
    int i = start;
    for (; i + 3 < end; i += 4) {
        int r0 = csr_row[i];
        int r1 = csr_row[i + 1];
        int r2 = csr_row[i + 2];
        int r3 = csr_row[i + 3];
        float4 v0 = static_cast<float4>(xq[((size_t)r0 << 4) + g]);
        float4 v1 = static_cast<float4>(xq[((size_t)r1 << 4) + g]);
        float4 v2 = static_cast<float4>(xq[((size_t)r2 << 4) + g]);
        float4 v3 = static_cast<float4>(xq[((size_t)r3 << 4) + g]);
        a0 += v0.x + v1.x + v2.x + v3.x;
        a1 += v0.y + v1.y + v2.y + v3.y;
        a2 += v0.z + v1.z + v2.z + v3.z;
        a3 += v0.w + v1.w + v2.w + v3.w;
    }
    for (; i < end; ++i) {
        int r = csr_row[i];
        float4 v = static_cast<float4>(xq[((size_t)r << 4) + g]);
        a0 += v.x; a1 += v.y; a2 += v.z; a3 += v.w;
    }
    float dv = dinv[grp];
    float s = dv * dv * (1.f / 16.f);
    union { _Float16 h[4]; short4 s4; } u;
    u.h[0] = (_Float16)(s * a0);
    u.h[1] = (_Float16)(s * a1);
    u.h[2] = (_Float16)(s * a2);
    u.h[3] = (_Float16)(s * a3);
    ((short4*)yh)[((size_t)grp << 4) + g] = u.s4;
}

// ---- conv layer 2 (listed nodes, fp16 operand, one 16-lane group per node) ----
__global__ __launch_bounds__(256) void conv2_kernel(const int* __restrict__ off,
                                                    const int* __restrict__ csr_row,
                                                    const float* __restrict__ dinv,
                                                    const _Float16* __restrict__ xh,
                                                    float* __restrict__ x2,
                                                    const int* __restrict__ list,
                                                    const int* __restrict__ count) {
    int gid = blockIdx.x * blockDim.x + threadIdx.x;
    int li = gid >> 4;
    int g = threadIdx.x & 15;
    if (li >= *count) return;
    int nd = list[li];
    int start = off[nd];
    int end = off[nd + 1];
    const short4* xh4 = (const short4*)xh;
    float a0 = 0.f, a1 = 0.f, a2 = 0.f, a3 = 0.f;
    int i = start;
    for (; i + 3 < end; i += 4) {
        int r0 = csr_row[i];
        int r1 = csr_row[i + 1];
        int r2 = csr_row[i + 2];
        int r3 = csr_row[i + 3];
        union { short4 s4; _Float16 h[4]; } u0, u1, u2, u3;
        u0.s4 = xh4[((size_t)r0 << 4) + g];
        u1.s4 = xh4[((size_t)r1 << 4) + g];
        u2.s4 = xh4[((size_t)r2 << 4) + g];
        u3.s4 = xh4[((size_t)r3 << 4) + g];
        a0 += (float)u0.h[0] + (float)u1.h[0] + (float)u2.h[0] + (float)u3.h[0];
        a1 += (float)u0.h[1] + (float)u1.h[1] + (float)u2.h[1] + (float)u3.h[1];
        a2 += (float)u0.h[2] + (float)u1.h[2] + (float)u2.h[2] + (float)u3.h[2];
        a3 += (float)u0.h[3] + (float)u1.h[3] + (float)u2.h[3] + (float)u3.h[3];
    }
    for (; i < end; ++i) {
        int r = csr_row[i];
        union { short4 s4; _Float16 h[4]; } u;
        u.s4 = xh4[((size_t)r << 4) + g];
        a0 += (float)u.h[0]; a1 += (float)u.h[1];
        a2 += (float)u.h[2]; a3 += (float)u.h[3];
    }
    float dv = dinv[nd];
    ((float4*)x2)[((size_t)nd << 4) + g] = make_float4(dv * a0, dv * a1, dv * a2, dv * a3);
}

// -------- fused node-wise: fp16 LDS weights + dot2; sorted list; branch-free prefetch ----
__global__ __launch_bounds__(256, 4) void fuse_kernel(
    const float* __restrict__ E, const float* __restrict__ E2,
    const float* __restrict__ W0, const float* __restrict__ b0,
    const float* __restrict__ W1, const float* __restrict__ b1,
    const float* __restrict__ AW, const float* __restrict__ ab,
    const float* __restrict__ qW,
    const _Float16* __restrict__ xn1, const float* __restrict__ sq,
    const float* x2, float* Z,
    const int* __restrict__ list, const int* __restrict__ count) {
    __shared__ __align__(16) _Float16 W0h[4096];   // quad-interleave: [(k>>2)*256 + j*4 + (k&3)]
    __shared__ __align__(16) _Float16 W1h[4096];
    __shared__ __align__(16) _Float16 AWh[4096];
    __shared__ float bb0[64], bb1[64], bab[64], qb[64];
    __shared__ __align__(16) _Float16 xb[4][64];
    __shared__ __align__(16) _Float16 hb[4][64];
    __shared__ __align__(16) _Float16 zpb[4][64];
    __shared__ __align__(16) _Float16 znb[4][64];

    int t = threadIdx.x;
    for (int idx = t; idx < 4096; idx += 256) {
        int j = idx >> 6, k = idx & 63;
        int dst = (k >> 2) * 256 + j * 4 + (k & 3);
        W0h[dst] = (_Float16)W0[idx];
        W1h[dst] = (_Float16)W1[idx];
        AWh[dst] = (_Float16)AW[idx];
    }
    if (t < 64) { bb0[t] = b0[t]; bb1[t] = b1[t]; bab[t] = ab[t]; qb[t] = qW[t]; }
    __syncthreads();   // weights staged once; node loop is wave-local

    const int lane = t & 63, w = t >> 6;
    const int cnt = *count;
    const int stride = gridDim.x * 4;
    int li = blockIdx.x * 4 + w;
    if (li >= cnt) return;

    // pipeline stage A (current node's data in registers); clamped branch-free loads
    int ndA = list[li];
    {
    }
    size_t bA0 = ((size_t)ndA << 6) + lane;
    float eA = E[bA0], e2A = E2[bA0], x2A = x2[bA0], sqA = sq[ndA];
    _Float16 xnA = xn1[bA0];

    for (; li < cnt; li += stride) {
        // prefetch next node's data with clamped index (no branch; extra loads harmless)
        int liB = li + stride; liB = (liB < cnt) ? liB : (cnt - 1);
        int ndB = list[liB];
        size_t bB = ((size_t)ndB << 6) + lane;
        float eB = E[bB], e2B = E2[bB], x2B = x2[bB], sqB = sq[ndB];
        _Float16 xnB = xn1[bB];

        size_t base = ((size_t)ndA << 6) + lane;
        float x1v = sqA * (float)xnA;
        float zp = (eA + x1v + x2A) * (1.f / 3.f);
        zpb[w][lane] = (_Float16)zp;
        xb[w][lane] = (_Float16)e2A;
        __builtin_amdgcn_wave_barrier();

        // h = relu(E2 @ W0.T + b0)
        float s0 = bb0[lane], s1 = 0.f;
#pragma unroll
        for (int k4 = 0; k4 < 16; k4++) {
            half4v w4 = *(const half4v*)&W0h[k4 * 256 + lane * 4];
            half4v x4 = *(const half4v*)&xb[w][k4 * 4];
            s0 = __builtin_amdgcn_fdot2((half2v){w4.x, w4.y}, (half2v){x4.x, x4.y}, s0, false);
            s1 = __builtin_amdgcn_fdot2((half2v){w4.z, w4.w}, (half2v){x4.z, x4.w}, s1, false);
        }
        float h = fmaxf(s0 + s1, 0.f);
        hb[w][lane] = (_Float16)h;
        __builtin_amdgcn_wave_barrier();

        // z_n = relu(h @ W1.T + b1)
        s0 = bb1[lane]; s1 = 0.f;
#pragma unroll
        for (int k4 = 0; k4 < 16; k4++) {
            half4v w4 = *(const half4v*)&W1h[k4 * 256 + lane * 4];
            half4v x4 = *(const half4v*)&hb[w][k4 * 4];
            s0 = __builtin_amdgcn_fdot2((half2v){w4.x, w4.y}, (half2v){x4.x, x4.y}, s0, false);
            s1 = __builtin_amdgcn_fdot2((half2v){w4.z, w4.w}, (half2v){x4.z, x4.w}, s1, false);
        }
        float zn = fmaxf(s0 + s1, 0.f);
        znb[w][lane] = (_Float16)zn;
        __builtin_amdgcn_wave_barrier();

        // attention scores for zp and zn (shared W read, 4 accumulators)
        float sp0 = bab[lane], sp1 = 0.f, sn0 = 0.f, sn1 = 0.f;
#pragma unroll
        for (int k4 = 0; k4 < 16; k4++) {
            half4v w4 = *(const half4v*)&AWh[k4 * 256 + lane * 4];
            half4v p4 = *(const half4v*)&zpb[w][k4 * 4];
            half4v n4 = *(const half4v*)&znb[w][k4 * 4];
            sp0 = __builtin_amdgcn_fdot2((half2v){w4.x, w4.y}, (half2v){p4.x, p4.y}, sp0, false);
            sp1 = __builtin_amdgcn_fdot2((half2v){w4.z, w4.w}, (half2v){p4.z, p4.w}, sp1, false);
            sn0 = __builtin_amdgcn_fdot2((half2v){w4.x, w4.y}, (half2v){n4.x, n4.y}, sn0, false);
            sn1 = __builtin_amdgcn_fdot2((half2v){w4.z, w4.w}, (half2v){n4.z, n4.w}, sn1, false);
        }
        float tp = tanhf(sp0 + sp1) * qb[lane];
        float tn = tanhf(bab[lane] + sn0 + sn1) * qb[lane];
        for (int m = 1; m < 64; m <<= 1) {
            tp += __shfl_xor(tp, m);
            tn += __shfl_xor(tn, m);
        }
        float mx = fmaxf(tp, tn);
        float ep = expf(tp - mx), en = expf(tn - mx);
        float inv = 1.f / (ep + en);
        Z[base] = (ep * zp + en * zn) * inv;
        __builtin_amdgcn_wave_barrier();

        // rotate pipeline
        ndA = ndB; eA = eB; e2A = e2B; xnA = xnB; x2A = x2B; sqA = sqB;
    }
}

// ---------------- loss ----------------
__global__ __launch_bounds__(256) void loss_kernel(const float* __restrict__ Z,
                                                   const float* __restrict__ wv,
                                                   const int* __restrict__ u,
                                                   const int* __restrict__ v,
                                                   const int* __restrict__ n,
                                                   float* __restrict__ out) {
    int wid = (blockIdx.x * blockDim.x + threadIdx.x) >> 6;
    int lane = threadIdx.x & 63;
    if (wid >= BATCH) return;
    float uu = Z[(size_t)u[wid] * DIM + lane];
    float vv = Z[(size_t)v[wid] * DIM + lane];
    float pos = uu * vv;
    for (int m = 1; m < 64; m <<= 1) pos += __shfl_xor(pos, m);
    float reg = uu * uu + vv * vv;
    float wval = wv[wid];
    float sgn = (wval > 0.f ? 1.f : 0.f) - (wval < 0.f ? 1.f : 0.f);
    float coef = -0.5f * sgn + 1.5f;
    float cp = coef * pos;
    float sb = 0.f;
    for (int k = 0; k < N_NEGS; k++) {
        int nid = n[wid * N_NEGS + k];
        float nn = Z[(size_t)nid * DIM + lane];
        float d = uu * nn;
        for (int m = 1; m < 64; m <<= 1) d += __shfl_xor(d, m);
        reg += nn * nn;
        float x = cp - d;
        float ls = (x >= 0.f) ? -log1pf(expf(-x)) : (x - log1pf(expf(x)));
        sb += ls;
    }
    for (int m = 1; m < 64; m <<= 1) reg += __shfl_xor(reg, m);
    if (lane == 0) atomicAdd(out, -sb + REG_COEF * reg);
}

extern "C" void kernel_launch(void* const* d_in, const int* in_sizes, int n_in,
                              void* d_out, int out_size, void* d_ws, size_t ws_size,
                              hipStream_t stream) {
    const float* E  = (const float*)d_in[0];
    const float* E2 = (const float*)d_in[1];
    const float* W0 = (const float*)d_in[2];
    const float* b0 = (const float*)d_in[3];
    const float* W1 = (const float*)d_in[4];
    const float* b1 = (const float*)d_in[5];
    const float* AW = (const float*)d_in[6];
    const float* ab = (const float*)d_in[7];
    const float* qW = (const float*)d_in[8];
    const float* wv = (const float*)d_in[9];
    const int* ei   = (const int*)d_in[10];
    const int* uu   = (const int*)d_in[11];
    const int* vv   = (const int*)d_in[12];
    const int* nn   = (const int*)d_in[13];
    const int* row = ei;
    const int* col = ei + N_EDGES;

    char* ws = (char*)d_ws;
    size_t p = 0;
    auto align_up = [](size_t x) { return (x + 255) & ~(size_t)255; };
    int* off        = (int*)(ws + p); p = align_up(p + (size_t)(NUM_NODES + 1) * 4);
    float* dinv     = (float*)(ws + p); p = align_up(p + (size_t)NUM_NODES * 4);
    float* sq       = (float*)(ws + p); p = align_up(p + (size_t)NUM_NODES * 4);
    int* hist       = (int*)(ws + p); p = align_up(p + (size_t)HSIZE * 4);
    int* partial    = (int*)(ws + p); p = align_up(p + (size_t)NB2 * 4);
    int* csr_row    = (int*)(ws + p); p = align_up(p + (size_t)N_EDGES * 4);
    int* flagi      = (int*)(ws + p); p = align_up(p + (size_t)NUM_NODES * 4);
    int* posb       = (int*)(ws + p); p = align_up(p + (size_t)NUM_NODES * 4);
    int* list       = (int*)(ws + p); p = align_up(p + (size_t)NLIST * 4);
    int* count      = (int*)(ws + p); p = align_up(p + 4);
    __hip_fp8x4_e4m3* xnE4 = (__hip_fp8x4_e4m3*)(ws + p); p = align_up(p + (size_t)NUM_NODES * DIM);
    _Float16* xn1   = (_Float16*)(ws + p); p = align_up(p + (size_t)NUM_NODES * DIM * 2);
    float* x2f      = (float*)(ws + p); p = align_up(p + (size_t)NUM_NODES * DIM * 4);
    float* Z = x2f;                      // alias: fuse reads x2f[nd] then writes Z[nd] same thread
    unsigned* staging = (unsigned*)x2f;  // alias: staging consumed by fill3 before conv2 writes x2f

    hipMemsetAsync(d_out, 0, sizeof(float), stream);
    hipMemsetAsync(flagi, 0, (size_t)NUM_NODES * 4, stream);

    histo_kernel<<<NT, 256, 0, stream>>>(col, hist);
    scan_partial_kernel<<<NB2, SCAN_B, 0, stream>>>(hist, partial, HSIZE);
    scan_base_kernel<<<1, 64, 0, stream>>>(partial, NB2, 2);
    scan_apply_kernel<<<NB2, SCAN_B, 0, stream>>>(hist, partial, HSIZE);
    partition_kernel<<<NT, 256, 0, stream>>>(row, col, hist, staging);
    fill3_kernel<<<NBK, 512, 0, stream>>>(hist, staging, E, off, dinv, sq, csr_row, xnE4);

    // sorted list: flag -> exclusive scan -> ordered emit
    flag_kernel<<<(NLIST + 255) / 256, 256, 0, stream>>>(uu, vv, nn, flagi);
    scan_partial_kernel<<<NB3, SCAN_B, 0, stream>>>(flagi, partial, NUM_NODES);
    scan_base_kernel<<<1, 64, 0, stream>>>(partial, NB3, 3);
    scan_apply2_kernel<<<NB3, SCAN_B, 0, stream>>>(flagi, posb, partial, NUM_NODES);
    emit_list_kernel<<<(NUM_NODES + 255) / 256, 256, 0, stream>>>(flagi, posb, list, count);

    conv1_kernel<<<(NUM_NODES * 16 + 255) / 256, 256, 0, stream>>>(off, csr_row, dinv, xnE4, xn1);
    conv2_kernel<<<(NLIST * 16 + 255) / 256, 256, 0, stream>>>(off, csr_row, dinv, xn1, x2f, list, count);

    fuse_kernel<<<1280, 256, 0, stream>>>(E, E2, W0, b0, W1, b1, AW, ab, qW,
                                          xn1, sq, x2f, Z, list, count);

    loss_kernel<<<BATCH * 64 / 256, 256, 0, stream>>>(Z, wv, uu, vv, nn, (float*)d_out);
}